// Round 1
// baseline (442.791 us; speedup 1.0000x reference)
//
#include <hip/hip_runtime.h>
#include <cstdint>
#include <cstddef>

#define NE 600000
#define NN 100000

typedef __attribute__((ext_vector_type(8)))  __bf16        bf16x8;
typedef __attribute__((ext_vector_type(16))) float         f32x16;
typedef __attribute__((ext_vector_type(8)))  unsigned short u16x8;

__device__ inline unsigned short f2bf(float f) {
    unsigned int u = __builtin_bit_cast(unsigned int, f);
    u += 0x7fffu + ((u >> 16) & 1u);   // round-to-nearest-even
    return (unsigned short)(u >> 16);
}

// Pack W (272x128 f32, row-major) into B-fragment layout:
// Wp[((k>>3)*128 + col)*8 + (k&7)] = bf16(W[k][col])
__global__ void pack_w(const float* __restrict__ W, unsigned short* __restrict__ Wp) {
    int t = blockIdx.x * 256 + threadIdx.x;       // 272*128 = 34816 threads
    if (t >= 272 * 128) return;
    int k = t >> 7, col = t & 127;
    Wp[((k >> 3) * 128 + col) * 8 + (k & 7)] = f2bf(W[t]);
}

// Convert x (100000x128 f32) to bf16. 8 elems/thread, 6250 blocks x 256.
__global__ void cvt_x(const float* __restrict__ x, unsigned short* __restrict__ xb) {
    size_t t = (size_t)(blockIdx.x * 256 + threadIdx.x) * 8;
    float4 a = *(const float4*)(x + t);
    float4 b = *(const float4*)(x + t + 4);
    u16x8 o;
    o[0] = f2bf(a.x); o[1] = f2bf(a.y); o[2] = f2bf(a.z); o[3] = f2bf(a.w);
    o[4] = f2bf(b.x); o[5] = f2bf(b.y); o[6] = f2bf(b.z); o[7] = f2bf(b.w);
    *(u16x8*)(xb + t) = o;
}

// Main gather-GEMM. Block = 256 threads = 4 waves; wave owns 32 edges.
// mfma_f32_32x32x16_bf16: A[row=l&31][k=(l>>5)*8+i], B[k=(l>>5)*8+i][col=l&31],
// C: col=l&31, row=(reg&3)+8*(reg>>2)+4*(l>>5).
template <bool USE_BF16X>
__global__ __launch_bounds__(256, 2) void edge_mm(
    const void* __restrict__ xsrc,              // bf16 xb (converted) or f32 x
    const unsigned short* __restrict__ Wp,      // packed W fragments (34 kb-blocks)
    const int* __restrict__ ei,                 // 2 x NE
    const float* __restrict__ ea,               // NE x 16
    const float* __restrict__ bias,             // 128
    float* __restrict__ out)                    // NE x 128
{
    __shared__ unsigned short Wl[32 * 128 * 8]; // exactly 64 KiB: k = 0..255

    // Stage W (k<256) into LDS once; edge-attr part (kb 32..33) read from L2.
    {
        const uint4* Wg = (const uint4*)Wp;
        uint4* Ws = (uint4*)Wl;
#pragma unroll
        for (int i = 0; i < 16; ++i)
            Ws[threadIdx.x + 256 * i] = Wg[threadIdx.x + 256 * i];
    }

    const int lane = threadIdx.x & 63;
    const int wave = threadIdx.x >> 6;
    const int r = lane & 31;       // edge row within wave tile / B column
    const int h = lane >> 5;       // half-wave: selects k-subblock of 8
    const long ebase = (long)blockIdx.x * 128 + wave * 32;

    __syncthreads();
    if (ebase >= NE) return;

    const int e = (int)ebase + r;
    const int src = ei[e];
    const int dst = ei[NE + e];

    f32x16 acc[4];
#pragma unroll
    for (int t = 0; t < 4; ++t)
#pragma unroll
        for (int i = 0; i < 16; ++i) acc[t][i] = 0.f;

    const bf16x8* Wv = (const bf16x8*)Wl;

    // ---- phase 1: h_i (k = 0..127), node = src ----
#pragma unroll
    for (int s = 0; s < 8; ++s) {
        bf16x8 a;
        if (USE_BF16X) {
            const bf16x8* ax = (const bf16x8*)((const unsigned short*)xsrc + (size_t)src * 128);
            a = ax[2 * s + h];
        } else {
            const float4* ax = (const float4*)((const float*)xsrc + (size_t)src * 128);
            float4 p = ax[(2 * s + h) * 2], q = ax[(2 * s + h) * 2 + 1];
            u16x8 o;
            o[0] = f2bf(p.x); o[1] = f2bf(p.y); o[2] = f2bf(p.z); o[3] = f2bf(p.w);
            o[4] = f2bf(q.x); o[5] = f2bf(q.y); o[6] = f2bf(q.z); o[7] = f2bf(q.w);
            a = __builtin_bit_cast(bf16x8, o);
        }
        const int S = s;
#pragma unroll
        for (int t = 0; t < 4; ++t) {
            bf16x8 b = Wv[(2 * S + h) * 128 + t * 32 + r];
            acc[t] = __builtin_amdgcn_mfma_f32_32x32x16_bf16(a, b, acc[t], 0, 0, 0);
        }
    }

    // ---- phase 2: h_j (k = 128..255), node = dst ----
#pragma unroll
    for (int s = 0; s < 8; ++s) {
        bf16x8 a;
        if (USE_BF16X) {
            const bf16x8* ax = (const bf16x8*)((const unsigned short*)xsrc + (size_t)dst * 128);
            a = ax[2 * s + h];
        } else {
            const float4* ax = (const float4*)((const float*)xsrc + (size_t)dst * 128);
            float4 p = ax[(2 * s + h) * 2], q = ax[(2 * s + h) * 2 + 1];
            u16x8 o;
            o[0] = f2bf(p.x); o[1] = f2bf(p.y); o[2] = f2bf(p.z); o[3] = f2bf(p.w);
            o[4] = f2bf(q.x); o[5] = f2bf(q.y); o[6] = f2bf(q.z); o[7] = f2bf(q.w);
            a = __builtin_bit_cast(bf16x8, o);
        }
        const int S = 8 + s;
#pragma unroll
        for (int t = 0; t < 4; ++t) {
            bf16x8 b = Wv[(2 * S + h) * 128 + t * 32 + r];
            acc[t] = __builtin_amdgcn_mfma_f32_32x32x16_bf16(a, b, acc[t], 0, 0, 0);
        }
    }

    // ---- phase 3: edge_attr (k = 256..271), B from global Wp (L2-hot) ----
    {
        const float4* ae = (const float4*)(ea + (size_t)e * 16);
        float4 p = ae[2 * h], q = ae[2 * h + 1];
        u16x8 o;
        o[0] = f2bf(p.x); o[1] = f2bf(p.y); o[2] = f2bf(p.z); o[3] = f2bf(p.w);
        o[4] = f2bf(q.x); o[5] = f2bf(q.y); o[6] = f2bf(q.z); o[7] = f2bf(q.w);
        bf16x8 a = __builtin_bit_cast(bf16x8, o);
        const bf16x8* Wg = (const bf16x8*)Wp;
#pragma unroll
        for (int t = 0; t < 4; ++t) {
            bf16x8 b = Wg[(32 + h) * 128 + t * 32 + r];
            acc[t] = __builtin_amdgcn_mfma_f32_32x32x16_bf16(a, b, acc[t], 0, 0, 0);
        }
    }

    // ---- epilogue: bias + store (each 32-lane half writes 128B contiguous) ----
    float* orow = out + (size_t)ebase * 128;
#pragma unroll
    for (int t = 0; t < 4; ++t) {
        float bv = bias[t * 32 + r];
#pragma unroll
        for (int i = 0; i < 16; ++i) {
            int row = (i & 3) + 8 * (i >> 2) + 4 * h;
            orow[(size_t)row * 128 + t * 32 + r] = acc[t][i] + bv;
        }
    }
}

extern "C" void kernel_launch(void* const* d_in, const int* in_sizes, int n_in,
                              void* d_out, int out_size, void* d_ws, size_t ws_size,
                              hipStream_t stream) {
    const float* x  = (const float*)d_in[0];
    const int*   ei = (const int*)d_in[1];
    const float* ea = (const float*)d_in[2];
    const float* W  = (const float*)d_in[3];
    const float* b  = (const float*)d_in[4];
    float* out = (float*)d_out;

    unsigned short* Wp = (unsigned short*)d_ws;                        // 69,632 B
    unsigned short* xb = (unsigned short*)((char*)d_ws + 69632);       // 25.6 MB
    const size_t need = 69632 + (size_t)NN * 128 * 2;

    hipLaunchKernelGGL(pack_w, dim3(136), dim3(256), 0, stream, W, Wp);

    if (ws_size >= need) {
        hipLaunchKernelGGL(cvt_x, dim3(6250), dim3(256), 0, stream, x, xb);
        hipLaunchKernelGGL((edge_mm<true>), dim3(4688), dim3(256), 0, stream,
                           (const void*)xb, Wp, ei, ea, b, out);
    } else {
        hipLaunchKernelGGL((edge_mm<false>), dim3(4688), dim3(256), 0, stream,
                           (const void*)x, Wp, ei, ea, b, out);
    }
}

// Round 2
// 434.814 us; speedup vs baseline: 1.0183x; 1.0183x over previous
//
#include <hip/hip_runtime.h>
#include <cstdint>
#include <cstddef>

#define NE 600000
#define NN 100000

typedef __attribute__((ext_vector_type(8)))  __bf16         bf16x8;
typedef __attribute__((ext_vector_type(16))) float          f32x16;
typedef __attribute__((ext_vector_type(8)))  unsigned short u16x8;

__device__ inline unsigned short f2bf(float f) {
    unsigned int u = __builtin_bit_cast(unsigned int, f);
    u += 0x7fffu + ((u >> 16) & 1u);   // round-to-nearest-even
    return (unsigned short)(u >> 16);
}

// Pack W (272x128 f32, row-major) into B-fragment layout:
// Wp[((k>>3)*128 + col)*8 + (k&7)] = bf16(W[k][col])
__global__ void pack_w(const float* __restrict__ W, unsigned short* __restrict__ Wp) {
    int t = blockIdx.x * 256 + threadIdx.x;       // 272*128 = 34816 threads
    if (t >= 272 * 128) return;
    int k = t >> 7, col = t & 127;
    Wp[((k >> 3) * 128 + col) * 8 + (k & 7)] = f2bf(W[t]);
}

// Convert x (100000x128 f32) to bf16. 8 elems/thread, 6250 blocks x 256.
__global__ void cvt_x(const float* __restrict__ x, unsigned short* __restrict__ xb) {
    size_t t = (size_t)(blockIdx.x * 256 + threadIdx.x) * 8;
    float4 a = *(const float4*)(x + t);
    float4 b = *(const float4*)(x + t + 4);
    u16x8 o;
    o[0] = f2bf(a.x); o[1] = f2bf(a.y); o[2] = f2bf(a.z); o[3] = f2bf(a.w);
    o[4] = f2bf(b.x); o[5] = f2bf(b.y); o[6] = f2bf(b.z); o[7] = f2bf(b.w);
    *(u16x8*)(xb + t) = o;
}

// s_waitcnt with vmcnt(n), lgkmcnt/expcnt untouched (gfx9 encoding:
// vmcnt[3:0]=bits3:0, expcnt=bits6:4, lgkmcnt=bits11:8, vmcnt[5:4]=bits15:14)
#define WAIT_VM(n) do { asm volatile("" ::: "memory");                      \
                        __builtin_amdgcn_s_waitcnt(0x0F70 | (n));           \
                        asm volatile("" ::: "memory"); } while (0)

// ARCH-B: coalesced async gather via global_load_lds, XOR-swizzled LDS slots,
// B-fragments from global Wp (L2-hot), no __syncthreads, no W staging.
// Block = 256 = 4 waves; wave owns 32 edges. LDS = 4 waves x (src+dst) x 8KB = 64KB
// -> 2 blocks/CU, 8 waves/CU, each wave with 16 async 256B-segment loads in flight.
__global__ __launch_bounds__(256, 2) void edge_mm2(
    const unsigned short* __restrict__ xb,      // NN x 128 bf16
    const unsigned short* __restrict__ Wp,      // packed W fragments (34 kb-blocks)
    const int* __restrict__ ei,                 // 2 x NE
    const float* __restrict__ ea,               // NE x 16
    const float* __restrict__ bias,             // 128
    float* __restrict__ out)                    // NE x 128
{
    // Abuf[wave][phase][row][slot*8 ..]; slot s of row r holds chunk (s ^ (r&15))
    __shared__ __attribute__((aligned(16))) unsigned short Abuf[4][2][32][128];

    const int lane = threadIdx.x & 63;
    const int wave = threadIdx.x >> 6;
    const int r  = lane & 31;       // edge row in wave tile / B column
    const int h  = lane >> 5;       // half-wave
    const int g4 = lane >> 4;       // row group (0..3) for cooperative gather
    const int sl = lane & 15;       // slot within row
    const int ebase = blockIdx.x * 128 + wave * 32;
    if (ebase >= NE) return;        // wave-uniform; last block has 2 active waves
    const int e = ebase + r;

    // ---- issue 8 src + 8 dst async row-gathers (coalesced 4 rows / instr) ----
#pragma unroll
    for (int i = 0; i < 8; ++i) {
        int row = 4 * i + g4;
        int nidx = ei[ebase + row];
        const unsigned short* gs = xb + (size_t)nidx * 128 + ((sl ^ (row & 15)) << 3);
        __builtin_amdgcn_global_load_lds(
            (const __attribute__((address_space(1))) void*)gs,
            (__attribute__((address_space(3))) void*)&Abuf[wave][0][4 * i][0],
            16, 0, 0);
    }
#pragma unroll
    for (int i = 0; i < 8; ++i) {
        int row = 4 * i + g4;
        int nidx = ei[NE + ebase + row];
        const unsigned short* gs = xb + (size_t)nidx * 128 + ((sl ^ (row & 15)) << 3);
        __builtin_amdgcn_global_load_lds(
            (const __attribute__((address_space(1))) void*)gs,
            (__attribute__((address_space(3))) void*)&Abuf[wave][1][4 * i][0],
            16, 0, 0);
    }

    // edge_attr for phase 3 (compiler inserts its own wait at first use)
    const float4* ae = (const float4*)(ea + (size_t)e * 16);
    float4 p = ae[2 * h], q = ae[2 * h + 1];

    f32x16 acc[4];
#pragma unroll
    for (int t = 0; t < 4; ++t)
#pragma unroll
        for (int i = 0; i < 16; ++i) acc[t][i] = 0.f;

    const bf16x8* Wg = (const bf16x8*)Wp;
    const int rm = r & 15;

    // ---- phase 1: h_i (kb = 0..15), src rows; dst loads stay in flight ----
    WAIT_VM(8);
#pragma unroll
    for (int S = 0; S < 8; ++S) {
        int kb = 2 * S + h;
        bf16x8 a = *(const bf16x8*)&Abuf[wave][0][r][(kb ^ rm) << 3];
#pragma unroll
        for (int t = 0; t < 4; ++t) {
            bf16x8 b = Wg[kb * 128 + t * 32 + r];
            acc[t] = __builtin_amdgcn_mfma_f32_32x32x16_bf16(a, b, acc[t], 0, 0, 0);
        }
    }

    // ---- phase 2: h_j (kb = 16..31), dst rows ----
    WAIT_VM(0);
#pragma unroll
    for (int S = 0; S < 8; ++S) {
        int kb = 2 * S + h;             // local chunk 0..15
        bf16x8 a = *(const bf16x8*)&Abuf[wave][1][r][(kb ^ rm) << 3];
#pragma unroll
        for (int t = 0; t < 4; ++t) {
            bf16x8 b = Wg[(16 + kb) * 128 + t * 32 + r];
            acc[t] = __builtin_amdgcn_mfma_f32_32x32x16_bf16(a, b, acc[t], 0, 0, 0);
        }
    }

    // ---- phase 3: edge_attr (kb = 32..33) ----
    {
        u16x8 o;
        o[0] = f2bf(p.x); o[1] = f2bf(p.y); o[2] = f2bf(p.z); o[3] = f2bf(p.w);
        o[4] = f2bf(q.x); o[5] = f2bf(q.y); o[6] = f2bf(q.z); o[7] = f2bf(q.w);
        bf16x8 a = __builtin_bit_cast(bf16x8, o);
#pragma unroll
        for (int t = 0; t < 4; ++t) {
            bf16x8 b = Wg[(32 + h) * 128 + t * 32 + r];
            acc[t] = __builtin_amdgcn_mfma_f32_32x32x16_bf16(a, b, acc[t], 0, 0, 0);
        }
    }

    // ---- epilogue: bias + store (two 128B segments per instruction) ----
    float* orow = out + (size_t)ebase * 128;
#pragma unroll
    for (int t = 0; t < 4; ++t) {
        float bv = bias[t * 32 + r];
#pragma unroll
        for (int i = 0; i < 16; ++i) {
            int row = (i & 3) + 8 * (i >> 2) + 4 * h;
            orow[(size_t)row * 128 + t * 32 + r] = acc[t][i] + bv;
        }
    }
}

// Fallback (ws too small for xb): R1 kernel reading f32 x directly, W in LDS.
__global__ __launch_bounds__(256, 2) void edge_mm_fb(
    const float* __restrict__ x,
    const unsigned short* __restrict__ Wp,
    const int* __restrict__ ei,
    const float* __restrict__ ea,
    const float* __restrict__ bias,
    float* __restrict__ out)
{
    __shared__ unsigned short Wl[32 * 128 * 8];
    {
        const uint4* Wg = (const uint4*)Wp;
        uint4* Ws = (uint4*)Wl;
#pragma unroll
        for (int i = 0; i < 16; ++i)
            Ws[threadIdx.x + 256 * i] = Wg[threadIdx.x + 256 * i];
    }
    const int lane = threadIdx.x & 63;
    const int wave = threadIdx.x >> 6;
    const int r = lane & 31;
    const int h = lane >> 5;
    const long ebase = (long)blockIdx.x * 128 + wave * 32;
    __syncthreads();
    if (ebase >= NE) return;
    const int e = (int)ebase + r;
    const int src = ei[e];
    const int dst = ei[NE + e];
    f32x16 acc[4];
#pragma unroll
    for (int t = 0; t < 4; ++t)
#pragma unroll
        for (int i = 0; i < 16; ++i) acc[t][i] = 0.f;
    const bf16x8* Wv = (const bf16x8*)Wl;
#pragma unroll
    for (int ph = 0; ph < 2; ++ph) {
        int node = ph ? dst : src;
#pragma unroll
        for (int s = 0; s < 8; ++s) {
            const float4* ax = (const float4*)(x + (size_t)node * 128);
            float4 pp = ax[(2 * s + h) * 2], qq = ax[(2 * s + h) * 2 + 1];
            u16x8 o;
            o[0] = f2bf(pp.x); o[1] = f2bf(pp.y); o[2] = f2bf(pp.z); o[3] = f2bf(pp.w);
            o[4] = f2bf(qq.x); o[5] = f2bf(qq.y); o[6] = f2bf(qq.z); o[7] = f2bf(qq.w);
            bf16x8 a = __builtin_bit_cast(bf16x8, o);
            int S = ph * 8 + s;
#pragma unroll
            for (int t = 0; t < 4; ++t) {
                bf16x8 b = Wv[(2 * S + h) * 128 + t * 32 + r];
                acc[t] = __builtin_amdgcn_mfma_f32_32x32x16_bf16(a, b, acc[t], 0, 0, 0);
            }
        }
    }
    {
        const float4* ae = (const float4*)(ea + (size_t)e * 16);
        float4 pp = ae[2 * h], qq = ae[2 * h + 1];
        u16x8 o;
        o[0] = f2bf(pp.x); o[1] = f2bf(pp.y); o[2] = f2bf(pp.z); o[3] = f2bf(pp.w);
        o[4] = f2bf(qq.x); o[5] = f2bf(qq.y); o[6] = f2bf(qq.z); o[7] = f2bf(qq.w);
        bf16x8 a = __builtin_bit_cast(bf16x8, o);
        const bf16x8* Wg = (const bf16x8*)Wp;
#pragma unroll
        for (int t = 0; t < 4; ++t) {
            bf16x8 b = Wg[(32 + h) * 128 + t * 32 + r];
            acc[t] = __builtin_amdgcn_mfma_f32_32x32x16_bf16(a, b, acc[t], 0, 0, 0);
        }
    }
    float* orow = out + (size_t)ebase * 128;
#pragma unroll
    for (int t = 0; t < 4; ++t) {
        float bv = bias[t * 32 + r];
#pragma unroll
        for (int i = 0; i < 16; ++i) {
            int row = (i & 3) + 8 * (i >> 2) + 4 * h;
            orow[(size_t)row * 128 + t * 32 + r] = acc[t][i] + bv;
        }
    }
}

extern "C" void kernel_launch(void* const* d_in, const int* in_sizes, int n_in,
                              void* d_out, int out_size, void* d_ws, size_t ws_size,
                              hipStream_t stream) {
    const float* x  = (const float*)d_in[0];
    const int*   ei = (const int*)d_in[1];
    const float* ea = (const float*)d_in[2];
    const float* W  = (const float*)d_in[3];
    const float* b  = (const float*)d_in[4];
    float* out = (float*)d_out;

    unsigned short* Wp = (unsigned short*)d_ws;                        // 69,632 B
    unsigned short* xb = (unsigned short*)((char*)d_ws + 69632);       // 25.6 MB
    const size_t need = 69632 + (size_t)NN * 128 * 2;

    hipLaunchKernelGGL(pack_w, dim3(136), dim3(256), 0, stream, W, Wp);

    if (ws_size >= need) {
        hipLaunchKernelGGL(cvt_x, dim3(6250), dim3(256), 0, stream, x, xb);
        hipLaunchKernelGGL(edge_mm2, dim3(4688), dim3(256), 0, stream,
                           xb, Wp, ei, ea, b, out);
    } else {
        hipLaunchKernelGGL(edge_mm_fb, dim3(4688), dim3(256), 0, stream,
                           x, Wp, ei, ea, b, out);
    }
}